// Round 5
// baseline (380.213 us; speedup 1.0000x reference)
//
#include <hip/hip_runtime.h>
#include <hip/hip_bf16.h>

#define TPB 256
// Margins (halved-score domain / squared-err domain). fp32 error bound is
// ~2e-5 at these magnitudes; 1e-3 gives ~50x headroom, so any row NOT
// flagged is provably decided identically by fp32 and fp64.
#define SCORE_MARGIN 1e-3f
#define ERR_MARGIN   1e-3f

// ---------------------------------------------------------------------------
// Kernel 1: fp32 screening pass. One thread per row. The codeword stream is
// wave-uniform, so it is read straight from global with a uniform loop index:
// the compiler's uniformity analysis turns these into s_load_dwordx8 /
// s_load_dword (scalar pipe + K$), eliminating the LDS-pipe bottleneck that
// capped R4 (36B/iter/wave through the per-CU LDS pipe, 618k bank conflicts).
// v_fma_f32 with one SGPR operand is legal, so the 16-FMA body stays pure
// VALU. One-iteration manual prefetch (clamped uniform index) hides s_load
// latency. Top-2 via v_med3 (1 inst; invariant sec<=best).
// Output d_out (float32): [final_vals (N*8) | final_idxs (N)].
// ---------------------------------------------------------------------------
__global__ __launch_bounds__(TPB) void e8p_screen(
    const float* __restrict__ X,
    const float* __restrict__ grid_part,
    const float* __restrict__ grid_part_norm,
    const int*   __restrict__ allcombo_idx,
    const int*   __restrict__ idx_map,
    float* __restrict__ out,
    int* __restrict__ ws,      // ws[0]=counter (pre-zeroed), ws[1..]=row ids
    int N, int G, int cap)
{
    const int i = blockIdx.x * TPB + threadIdx.x;
    if (i >= N) return;

    const float4* X4 = (const float4*)(X + (size_t)i * 8);
    float4 a = X4[0], b = X4[1];
    float x[8] = {a.x, a.y, a.z, a.w, b.x, b.y, b.z, b.w};

    // Sign prep (fp32 signs == fp64 signs: correctly-rounded add can't
    // cross zero; exact-zero gives the same >=0 decision in both).
    float yp[8], ym[8], yap[8], yam[8];
    int negp = 0, negm = 0;
#pragma unroll
    for (int j = 0; j < 8; ++j) {
        yp[j] = x[j] + 0.25f;
        ym[j] = x[j] - 0.25f;
        if (yp[j] < 0.0f) negp |= (1 << (7 - j));
        if (ym[j] < 0.0f) negm |= (1 << (7 - j));
        yap[j] = fabsf(yp[j]);
        yam[j] = fabsf(ym[j]);
    }
    int mintp = negp, mintm = negm;
    if (__popc(negp) & 1) { yap[0] = -yap[0]; mintp ^= 128; }
    if (__popc(negm) & 1) { yam[0] = -yam[0]; mintm ^= 128; }

    // Prefetch codeword 0 (uniform -> scalar loads).
    float cg[8], cnrm;
#pragma unroll
    for (int k = 0; k < 8; ++k) cg[k] = grid_part[k];
    cnrm = grid_part_norm[0];

    // fp32 argmax with top-2 tracking (first-max-wins).
    float bestp = -1e30f, bestm = -1e30f;
    float secp = -1e30f, secm = -1e30f;
    int qp = 0, qm = 0;
#pragma unroll 2
    for (int j = 0; j < G; ++j) {
        float g[8];
#pragma unroll
        for (int k = 0; k < 8; ++k) g[k] = cg[k];
        const float n0 = cnrm;

        // Prefetch next codeword (clamped uniform index; scalar cselect).
        const int jn = (j + 1 < G) ? (j + 1) : 0;
#pragma unroll
        for (int k = 0; k < 8; ++k) cg[k] = grid_part[(size_t)jn * 8 + k];
        cnrm = grid_part_norm[jn];

        const float mn = -0.5f * n0;   // score' = dot - n/2 (same ordering)
        float dp, dm;
        dp = fmaf(yap[0], g[0], mn);   dm = fmaf(yam[0], g[0], mn);
        dp = fmaf(yap[1], g[1], dp);   dm = fmaf(yam[1], g[1], dm);
        dp = fmaf(yap[2], g[2], dp);   dm = fmaf(yam[2], g[2], dm);
        dp = fmaf(yap[3], g[3], dp);   dm = fmaf(yam[3], g[3], dm);
        dp = fmaf(yap[4], g[4], dp);   dm = fmaf(yam[4], g[4], dm);
        dp = fmaf(yap[5], g[5], dp);   dm = fmaf(yam[5], g[5], dm);
        dp = fmaf(yap[6], g[6], dp);   dm = fmaf(yam[6], g[6], dm);
        dp = fmaf(yap[7], g[7], dp);   dm = fmaf(yam[7], g[7], dm);

        // top-2: sec = med3(new, best, sec) (valid since sec <= best);
        // best = max; idx on strict > (first-max-wins like np.argmax).
        const bool gtp = dp > bestp;
        const bool gtm = dm > bestm;
        secp = __builtin_amdgcn_fmed3f(dp, bestp, secp);
        secm = __builtin_amdgcn_fmed3f(dm, bestm, secm);
        bestp = fmaxf(bestp, dp);
        bestm = fmaxf(bestm, dm);
        qp = gtp ? j : qp;
        qm = gtm ? j : qm;
    }

    // Epilogue (fp32): rebuild vals, squared errors.
    const float* gp_ = grid_part + (size_t)qp * 8;
    const float* gm_ = grid_part + (size_t)qm * 8;
    float vp[8], vm[8];
    float ep2 = 0.0f, em2 = 0.0f;
#pragma unroll
    for (int j = 0; j < 8; ++j) {
        const float maskp = ((mintp >> (7 - j)) & 1) ? -1.0f : 1.0f;
        const float maskm = ((mintm >> (7 - j)) & 1) ? -1.0f : 1.0f;
        vp[j] = gp_[j] * maskp;
        vm[j] = gm_[j] * maskm;
        const float dpj = yp[j] - vp[j];
        const float dmj = ym[j] - vm[j];
        ep2 = fmaf(dpj, dpj, ep2);
        em2 = fmaf(dmj, dmj, em2);
    }

    const bool close = ((bestp - secp) < SCORE_MARGIN) |
                       ((bestm - secm) < SCORE_MARGIN) |
                       (fabsf(ep2 - em2) < ERR_MARGIN);
    if (close) {
        int slot = atomicAdd(ws, 1);
        if (slot < cap) ws[1 + slot] = i;
    }

    const bool which = ep2 < em2;  // == sqrt compare; safe when not flagged

    const int rowp = idx_map[mintp];
    const int rowm = idx_map[mintm];
    const int pi = allcombo_idx[(size_t)rowp * G + qp];
    const int mi = allcombo_idx[(size_t)rowm * G + qm];
    const float idxval = which ? (float)pi : (float)(mi - 32768);

    float* vout = out + (size_t)i * 8;
#pragma unroll
    for (int j = 0; j < 8; ++j) {
        vout[j] = which ? (vp[j] - 0.25f) : (vm[j] + 0.25f);
    }
    out[(size_t)N * 8 + i] = idxval;
}

// ---------------------------------------------------------------------------
// Kernel 2: fp64 fixup — exact replica of the round-2 arithmetic (verified
// absmax 0.0) for flagged rows only. One WAVE per row: lanes split the
// G-loop 64-way, then (max-score, min-index) shuffle reduce = np.argmax
// first-max-wins. Codebook read from global (L2-resident, coalesced).
// ---------------------------------------------------------------------------
__global__ __launch_bounds__(TPB) void e8p_fix(
    const float* __restrict__ X,
    const float* __restrict__ grid_part,
    const float* __restrict__ grid_part_norm,
    const int*   __restrict__ allcombo_idx,
    const int*   __restrict__ idx_map,
    float* __restrict__ out,
    const int* __restrict__ ws,
    int N, int G, int cap)
{
    const int count = min(ws[0], cap);
    const int lane  = threadIdx.x & 63;
    const int wave  = (blockIdx.x * blockDim.x + threadIdx.x) >> 6;
    const int nwave = (gridDim.x * blockDim.x) >> 6;

    for (int r = wave; r < count; r += nwave) {
        const int i = ws[1 + r];

        const float4* X4 = (const float4*)(X + (size_t)i * 8);
        float4 a = X4[0], b = X4[1];
        float x[8] = {a.x, a.y, a.z, a.w, b.x, b.y, b.z, b.w};

        double yap[8], yam[8];
        int negp = 0, negm = 0;
#pragma unroll
        for (int j = 0; j < 8; ++j) {
            const double xd = (double)x[j];
            const double ypj = xd + 0.25;
            const double ymj = xd - 0.25;
            if (ypj < 0.0) negp |= (1 << (7 - j));
            if (ymj < 0.0) negm |= (1 << (7 - j));
            yap[j] = fabs(ypj);
            yam[j] = fabs(ymj);
        }
        int mintp = negp, mintm = negm;
        if (__popc(negp) & 1) { yap[0] = -yap[0]; mintp ^= 128; }
        if (__popc(negm) & 1) { yam[0] = -yam[0]; mintm ^= 128; }

        double bestp = -1e300, bestm = -1e300;
        int qp = 0x7fffffff, qm = 0x7fffffff;
        for (int j = lane; j < G; j += 64) {
            const float4 g0 = *(const float4*)(grid_part + (size_t)j * 8);
            const float4 g1 = *(const float4*)(grid_part + (size_t)j * 8 + 4);
            const double n = (double)grid_part_norm[j];
            const double t0 = (double)g0.x, t1 = (double)g0.y,
                         t2 = (double)g0.z, t3 = (double)g0.w,
                         t4 = (double)g1.x, t5 = (double)g1.y,
                         t6 = (double)g1.z, t7 = (double)g1.w;
            double dp, dm;
            dp = yap[0] * t0;           dm = yam[0] * t0;
            dp = fma(yap[1], t1, dp);   dm = fma(yam[1], t1, dm);
            dp = fma(yap[2], t2, dp);   dm = fma(yam[2], t2, dm);
            dp = fma(yap[3], t3, dp);   dm = fma(yam[3], t3, dm);
            dp = fma(yap[4], t4, dp);   dm = fma(yam[4], t4, dm);
            dp = fma(yap[5], t5, dp);   dm = fma(yam[5], t5, dm);
            dp = fma(yap[6], t6, dp);   dm = fma(yam[6], t6, dm);
            dp = fma(yap[7], t7, dp);   dm = fma(yam[7], t7, dm);
            const double sp = 2.0 * dp - n;
            const double sm = 2.0 * dm - n;
            if (sp > bestp) { bestp = sp; qp = j; }
            if (sm > bestm) { bestm = sm; qm = j; }
        }
        // (max score, min index) butterfly reduce == np.argmax first-max-wins
#pragma unroll
        for (int off = 32; off > 0; off >>= 1) {
            double ob = __shfl_xor(bestp, off, 64);
            int    oq = __shfl_xor(qp, off, 64);
            if (ob > bestp || (ob == bestp && oq < qp)) { bestp = ob; qp = oq; }
            ob = __shfl_xor(bestm, off, 64);
            oq = __shfl_xor(qm, off, 64);
            if (ob > bestm || (ob == bestm && oq < qm)) { bestm = ob; qm = oq; }
        }

        if (lane == 0) {
            const float* gp_ = grid_part + (size_t)qp * 8;
            const float* gm_ = grid_part + (size_t)qm * 8;
            double vp[8], vm[8];
            double ep2 = 0.0, em2 = 0.0;
#pragma unroll
            for (int j = 0; j < 8; ++j) {
                const double maskp = ((mintp >> (7 - j)) & 1) ? -1.0 : 1.0;
                const double maskm = ((mintm >> (7 - j)) & 1) ? -1.0 : 1.0;
                vp[j] = (double)gp_[j] * maskp;
                vm[j] = (double)gm_[j] * maskm;
                const double xd = (double)x[j];
                const double dpj = (xd + 0.25) - vp[j];
                const double dmj = (xd - 0.25) - vm[j];
                ep2 += dpj * dpj;
                em2 += dmj * dmj;
            }
            const double ep = sqrt(ep2), em = sqrt(em2);
            const bool which = ep < em;

            const int rowp = idx_map[mintp];
            const int rowm = idx_map[mintm];
            const int pi = allcombo_idx[(size_t)rowp * G + qp];
            const int mi = allcombo_idx[(size_t)rowm * G + qm];
            const float idxval = which ? (float)pi : (float)(mi - 32768);

            float* vout = out + (size_t)i * 8;
#pragma unroll
            for (int j = 0; j < 8; ++j) {
                const double v = which ? (vp[j] - 0.25) : (vm[j] + 0.25);
                vout[j] = (float)v;
            }
            out[(size_t)N * 8 + i] = idxval;
        }
    }
}

extern "C" void kernel_launch(void* const* d_in, const int* in_sizes, int n_in,
                              void* d_out, int out_size, void* d_ws, size_t ws_size,
                              hipStream_t stream) {
    const float* X    = (const float*)d_in[0];
    const float* gp   = (const float*)d_in[1];
    const float* gn   = (const float*)d_in[2];
    const int*   aci  = (const int*)d_in[3];
    const int*   imap = (const int*)d_in[4];
    // d_in[5] (int_map) and d_in[6] (grid_idx_map) are folded analytically.

    const int N = in_sizes[0] / 8;
    const int G = in_sizes[1] / 8;
    const int blocks = (N + TPB - 1) / TPB;

    int* ws = (int*)d_ws;
    long long capl = (long long)(ws_size / 4) - 1;
    if (capl < 0) capl = 0;
    if (capl > N) capl = N;
    const int cap = (int)capl;

    hipMemsetAsync(ws, 0, sizeof(int), stream);  // zero the flag counter

    hipLaunchKernelGGL(e8p_screen, dim3(blocks), dim3(TPB), 0, stream,
                       X, gp, gn, aci, imap, (float*)d_out, ws, N, G, cap);
    // 256 blocks x 256 thr = 1024 waves; grid-strides if count > 1024.
    hipLaunchKernelGGL(e8p_fix, dim3(256), dim3(TPB), 0, stream,
                       X, gp, gn, aci, imap, (float*)d_out, ws, N, G, cap);
}

// Round 6
// 353.070 us; speedup vs baseline: 1.0769x; 1.0769x over previous
//
#include <hip/hip_runtime.h>
#include <hip/hip_bf16.h>

#define TPB_S 128   // screen block (2 waves); 2 rows/thread -> 512 blocks
#define TPB_F 256
#define ROWS  2
// fp32 score/err error bound at these magnitudes is ~2e-5; 1e-3 = 50x headroom.
#define SCORE_MARGIN 1e-3f
#define ERR_MARGIN   1e-3f

// ---------------------------------------------------------------------------
// Kernel 1: fp32 screen. Codewords bf16-packed in LDS (all codebook values
// and norms are exact in bf16): 1x ds_read_b128 (8 dims) + 1x ds_read_b32
// (-norm/2) per codeword = 20B/iter, amortized over 2 rows/thread (32 FMA),
// vs R4's 36B/row/iter that saturated the LDS pipe. Broadcast reads are
// conflict-free. Coincident rows (both branches -> same lattice point,
// exact fp32 detect) take which=false deterministically (fp64 ref gives
// pe==me bit-exactly) and are NOT err-flagged.
// Output d_out (float32): [final_vals (N*8) | final_idxs (N)].
// ---------------------------------------------------------------------------
__global__ __launch_bounds__(TPB_S, 1) void e8p_screen(
    const float* __restrict__ X,
    const float* __restrict__ grid_part,
    const float* __restrict__ grid_part_norm,
    const int*   __restrict__ allcombo_idx,
    const int*   __restrict__ idx_map,
    float* __restrict__ out,
    int* __restrict__ ws,      // ws[0]=counter (pre-zeroed), ws[1..]=row ids
    int N, int G, int cap)
{
    extern __shared__ __align__(16) unsigned int smem[];
    unsigned int* cw = smem;               // 4*G uints = 8*G bf16 (16B/codeword)
    float* cn = (float*)(smem + 4 * G);    // G floats: -0.5*norm

    const int tid = threadIdx.x;
    // Stage: pack two fp32 -> one uint of 2 bf16 (truncation exact here).
    for (int k = tid; k < 4 * G; k += TPB_S) {
        const unsigned int u0 = __float_as_uint(grid_part[2 * k]);
        const unsigned int u1 = __float_as_uint(grid_part[2 * k + 1]);
        cw[k] = (u0 >> 16) | (u1 & 0xffff0000u);
    }
    for (int k = tid; k < G; k += TPB_S) cn[k] = -0.5f * grid_part_norm[k];
    __syncthreads();

    // Two rows per thread: i(r) = blockIdx*256 + tid + r*128 (coalesced).
    int rowid[ROWS];
    float yp[ROWS][8], ym[ROWS][8], yap[ROWS][8], yam[ROWS][8];
    int mintp[ROWS], mintm[ROWS];
    float bestp[ROWS], bestm[ROWS], secp[ROWS], secm[ROWS];
    int qp[ROWS], qm[ROWS];

#pragma unroll
    for (int r = 0; r < ROWS; ++r) {
        const int i = blockIdx.x * (TPB_S * ROWS) + tid + r * TPB_S;
        rowid[r] = i;
        if (i >= N) { rowid[r] = -1; continue; }
        const float4* X4 = (const float4*)(X + (size_t)i * 8);
        float4 a = X4[0], b = X4[1];
        float x[8] = {a.x, a.y, a.z, a.w, b.x, b.y, b.z, b.w};
        int negp = 0, negm = 0;
#pragma unroll
        for (int j = 0; j < 8; ++j) {
            yp[r][j] = x[j] + 0.25f;       // Sterbenz: exact near the sign
            ym[r][j] = x[j] - 0.25f;       // boundary -> sign bits match fp64
            if (yp[r][j] < 0.0f) negp |= (1 << (7 - j));
            if (ym[r][j] < 0.0f) negm |= (1 << (7 - j));
            yap[r][j] = fabsf(yp[r][j]);
            yam[r][j] = fabsf(ym[r][j]);
        }
        mintp[r] = negp; mintm[r] = negm;
        if (__popc(negp) & 1) { yap[r][0] = -yap[r][0]; mintp[r] ^= 128; }
        if (__popc(negm) & 1) { yam[r][0] = -yam[r][0]; mintm[r] ^= 128; }
        bestp[r] = -1e30f; bestm[r] = -1e30f;
        secp[r] = -1e30f;  secm[r] = -1e30f;
        qp[r] = 0; qm[r] = 0;
    }

    const uint4* cw4 = (const uint4*)cw;
    // 1-deep prefetch of the broadcast codeword stream.
    uint4 c16 = cw4[0];
    float mn  = cn[0];

#pragma unroll 2
    for (int j = 0; j < G; ++j) {
        const uint4 cur = c16;
        const float n0 = mn;
        const int jn = (j + 1 < G) ? (j + 1) : 0;
        c16 = cw4[jn];
        mn  = cn[jn];

        // Decode 8 bf16 -> fp32 (exact): lo = u<<16, hi = u&0xffff0000.
        float g[8];
        g[0] = __uint_as_float(cur.x << 16);
        g[1] = __uint_as_float(cur.x & 0xffff0000u);
        g[2] = __uint_as_float(cur.y << 16);
        g[3] = __uint_as_float(cur.y & 0xffff0000u);
        g[4] = __uint_as_float(cur.z << 16);
        g[5] = __uint_as_float(cur.z & 0xffff0000u);
        g[6] = __uint_as_float(cur.w << 16);
        g[7] = __uint_as_float(cur.w & 0xffff0000u);

#pragma unroll
        for (int r = 0; r < ROWS; ++r) {
            float dp = fmaf(yap[r][0], g[0], n0);
            float dm = fmaf(yam[r][0], g[0], n0);
#pragma unroll
            for (int k = 1; k < 8; ++k) {
                dp = fmaf(yap[r][k], g[k], dp);
                dm = fmaf(yam[r][k], g[k], dm);
            }
            const bool gtp = dp > bestp[r];
            const bool gtm = dm > bestm[r];
            secp[r] = __builtin_amdgcn_fmed3f(dp, bestp[r], secp[r]);
            secm[r] = __builtin_amdgcn_fmed3f(dm, bestm[r], secm[r]);
            bestp[r] = fmaxf(bestp[r], dp);
            bestm[r] = fmaxf(bestm[r], dm);
            qp[r] = gtp ? j : qp[r];
            qm[r] = gtm ? j : qm[r];
        }
    }

#pragma unroll
    for (int r = 0; r < ROWS; ++r) {
        const int i = rowid[r];
        if (i < 0) continue;

        // Decode winning codewords from LDS (per-lane gather, one-off).
        const uint4 cp = cw4[qp[r]];
        const uint4 cm = cw4[qm[r]];
        float gpv[8], gmv[8];
        gpv[0] = __uint_as_float(cp.x << 16); gpv[1] = __uint_as_float(cp.x & 0xffff0000u);
        gpv[2] = __uint_as_float(cp.y << 16); gpv[3] = __uint_as_float(cp.y & 0xffff0000u);
        gpv[4] = __uint_as_float(cp.z << 16); gpv[5] = __uint_as_float(cp.z & 0xffff0000u);
        gpv[6] = __uint_as_float(cp.w << 16); gpv[7] = __uint_as_float(cp.w & 0xffff0000u);
        gmv[0] = __uint_as_float(cm.x << 16); gmv[1] = __uint_as_float(cm.x & 0xffff0000u);
        gmv[2] = __uint_as_float(cm.y << 16); gmv[3] = __uint_as_float(cm.y & 0xffff0000u);
        gmv[4] = __uint_as_float(cm.z << 16); gmv[5] = __uint_as_float(cm.z & 0xffff0000u);
        gmv[6] = __uint_as_float(cm.w << 16); gmv[7] = __uint_as_float(cm.w & 0xffff0000u);

        float vp[8], vm[8];
        float ep2 = 0.0f, em2 = 0.0f;
        bool coin = true;
#pragma unroll
        for (int j = 0; j < 8; ++j) {
            const float maskp = ((mintp[r] >> (7 - j)) & 1) ? -1.0f : 1.0f;
            const float maskm = ((mintm[r] >> (7 - j)) & 1) ? -1.0f : 1.0f;
            vp[j] = gpv[j] * maskp;
            vm[j] = gmv[j] * maskm;
            coin = coin && ((vp[j] - 0.25f) == (vm[j] + 0.25f)); // exact fp32
            const float dpj = yp[r][j] - vp[j];
            const float dmj = ym[r][j] - vm[j];
            ep2 = fmaf(dpj, dpj, ep2);
            em2 = fmaf(dmj, dmj, em2);
        }

        // Coincident -> fp64 ref has pe==me bit-exactly -> which=false.
        const bool close = ((bestp[r] - secp[r]) < SCORE_MARGIN) |
                           ((bestm[r] - secm[r]) < SCORE_MARGIN) |
                           (!coin && (fabsf(ep2 - em2) < ERR_MARGIN));
        if (close) {
            int slot = atomicAdd(ws, 1);
            if (slot < cap) ws[1 + slot] = i;
        }
        const bool which = coin ? false : (ep2 < em2);

        const int rowp = idx_map[mintp[r]];
        const int rowm = idx_map[mintm[r]];
        const int pi = allcombo_idx[(size_t)rowp * G + qp[r]];
        const int mi = allcombo_idx[(size_t)rowm * G + qm[r]];
        const float idxval = which ? (float)pi : (float)(mi - 32768);

        float* vout = out + (size_t)i * 8;
#pragma unroll
        for (int j = 0; j < 8; ++j) {
            vout[j] = which ? (vp[j] - 0.25f) : (vm[j] + 0.25f);
        }
        out[(size_t)N * 8 + i] = idxval;
    }
}

// ---------------------------------------------------------------------------
// Kernel 2: fp64 fixup — exact replica of the round-2 arithmetic (verified
// absmax 0.0) for flagged rows. One WAVE per row; (max,min-idx) reduce ==
// np.argmax first-max-wins. Handles coincident rows correctly (ep==em
// bit-exact -> which=false).
// ---------------------------------------------------------------------------
__global__ __launch_bounds__(TPB_F) void e8p_fix(
    const float* __restrict__ X,
    const float* __restrict__ grid_part,
    const float* __restrict__ grid_part_norm,
    const int*   __restrict__ allcombo_idx,
    const int*   __restrict__ idx_map,
    float* __restrict__ out,
    const int* __restrict__ ws,
    int N, int G, int cap)
{
    const int count = min(ws[0], cap);
    const int lane  = threadIdx.x & 63;
    const int wave  = (blockIdx.x * blockDim.x + threadIdx.x) >> 6;
    const int nwave = (gridDim.x * blockDim.x) >> 6;

    for (int r = wave; r < count; r += nwave) {
        const int i = ws[1 + r];

        const float4* X4 = (const float4*)(X + (size_t)i * 8);
        float4 a = X4[0], b = X4[1];
        float x[8] = {a.x, a.y, a.z, a.w, b.x, b.y, b.z, b.w};

        double yap[8], yam[8];
        int negp = 0, negm = 0;
#pragma unroll
        for (int j = 0; j < 8; ++j) {
            const double xd = (double)x[j];
            const double ypj = xd + 0.25;
            const double ymj = xd - 0.25;
            if (ypj < 0.0) negp |= (1 << (7 - j));
            if (ymj < 0.0) negm |= (1 << (7 - j));
            yap[j] = fabs(ypj);
            yam[j] = fabs(ymj);
        }
        int mintp = negp, mintm = negm;
        if (__popc(negp) & 1) { yap[0] = -yap[0]; mintp ^= 128; }
        if (__popc(negm) & 1) { yam[0] = -yam[0]; mintm ^= 128; }

        double bestp = -1e300, bestm = -1e300;
        int qp = 0x7fffffff, qm = 0x7fffffff;
        for (int j = lane; j < G; j += 64) {
            const float4 g0 = *(const float4*)(grid_part + (size_t)j * 8);
            const float4 g1 = *(const float4*)(grid_part + (size_t)j * 8 + 4);
            const double n = (double)grid_part_norm[j];
            const double t0 = (double)g0.x, t1 = (double)g0.y,
                         t2 = (double)g0.z, t3 = (double)g0.w,
                         t4 = (double)g1.x, t5 = (double)g1.y,
                         t6 = (double)g1.z, t7 = (double)g1.w;
            double dp, dm;
            dp = yap[0] * t0;           dm = yam[0] * t0;
            dp = fma(yap[1], t1, dp);   dm = fma(yam[1], t1, dm);
            dp = fma(yap[2], t2, dp);   dm = fma(yam[2], t2, dm);
            dp = fma(yap[3], t3, dp);   dm = fma(yam[3], t3, dm);
            dp = fma(yap[4], t4, dp);   dm = fma(yam[4], t4, dm);
            dp = fma(yap[5], t5, dp);   dm = fma(yam[5], t5, dm);
            dp = fma(yap[6], t6, dp);   dm = fma(yam[6], t6, dm);
            dp = fma(yap[7], t7, dp);   dm = fma(yam[7], t7, dm);
            const double sp = 2.0 * dp - n;
            const double sm = 2.0 * dm - n;
            if (sp > bestp) { bestp = sp; qp = j; }
            if (sm > bestm) { bestm = sm; qm = j; }
        }
#pragma unroll
        for (int off = 32; off > 0; off >>= 1) {
            double ob = __shfl_xor(bestp, off, 64);
            int    oq = __shfl_xor(qp, off, 64);
            if (ob > bestp || (ob == bestp && oq < qp)) { bestp = ob; qp = oq; }
            ob = __shfl_xor(bestm, off, 64);
            oq = __shfl_xor(qm, off, 64);
            if (ob > bestm || (ob == bestm && oq < qm)) { bestm = ob; qm = oq; }
        }

        if (lane == 0) {
            const float* gp_ = grid_part + (size_t)qp * 8;
            const float* gm_ = grid_part + (size_t)qm * 8;
            double vp[8], vm[8];
            double ep2 = 0.0, em2 = 0.0;
#pragma unroll
            for (int j = 0; j < 8; ++j) {
                const double maskp = ((mintp >> (7 - j)) & 1) ? -1.0 : 1.0;
                const double maskm = ((mintm >> (7 - j)) & 1) ? -1.0 : 1.0;
                vp[j] = (double)gp_[j] * maskp;
                vm[j] = (double)gm_[j] * maskm;
                const double xd = (double)x[j];
                const double dpj = (xd + 0.25) - vp[j];
                const double dmj = (xd - 0.25) - vm[j];
                ep2 += dpj * dpj;
                em2 += dmj * dmj;
            }
            const double ep = sqrt(ep2), em = sqrt(em2);
            const bool which = ep < em;

            const int rowp = idx_map[mintp];
            const int rowm = idx_map[mintm];
            const int pi = allcombo_idx[(size_t)rowp * G + qp];
            const int mi = allcombo_idx[(size_t)rowm * G + qm];
            const float idxval = which ? (float)pi : (float)(mi - 32768);

            float* vout = out + (size_t)i * 8;
#pragma unroll
            for (int j = 0; j < 8; ++j) {
                const double v = which ? (vp[j] - 0.25) : (vm[j] + 0.25);
                vout[j] = (float)v;
            }
            out[(size_t)N * 8 + i] = idxval;
        }
    }
}

extern "C" void kernel_launch(void* const* d_in, const int* in_sizes, int n_in,
                              void* d_out, int out_size, void* d_ws, size_t ws_size,
                              hipStream_t stream) {
    const float* X    = (const float*)d_in[0];
    const float* gp   = (const float*)d_in[1];
    const float* gn   = (const float*)d_in[2];
    const int*   aci  = (const int*)d_in[3];
    const int*   imap = (const int*)d_in[4];
    // d_in[5] (int_map) and d_in[6] (grid_idx_map) are folded analytically.

    const int N = in_sizes[0] / 8;
    const int G = in_sizes[1] / 8;
    const int blocks = (N + TPB_S * ROWS - 1) / (TPB_S * ROWS);
    // LDS: 4G uints (bf16-packed codewords) + G floats (-norm/2)
    const size_t shmem = (size_t)(4 * G) * 4 + (size_t)G * 4;

    int* ws = (int*)d_ws;
    long long capl = (long long)(ws_size / 4) - 1;
    if (capl < 0) capl = 0;
    if (capl > N) capl = N;
    const int cap = (int)capl;

    hipMemsetAsync(ws, 0, sizeof(int), stream);  // zero the flag counter

    hipLaunchKernelGGL(e8p_screen, dim3(blocks), dim3(TPB_S), shmem, stream,
                       X, gp, gn, aci, imap, (float*)d_out, ws, N, G, cap);
    hipLaunchKernelGGL(e8p_fix, dim3(256), dim3(TPB_F), 0, stream,
                       X, gp, gn, aci, imap, (float*)d_out, ws, N, G, cap);
}

// Round 7
// 197.934 us; speedup vs baseline: 1.9209x; 1.7838x over previous
//
#include <hip/hip_runtime.h>
#include <hip/hip_bf16.h>

typedef __attribute__((ext_vector_type(8))) short bf16x8;
typedef __attribute__((ext_vector_type(4))) float f32x4;

#define TPB 256
// MFMA score error bound ~2.3e-4 (bf16 hi/lo split + fp32 accumulate);
// 1e-3 margin gives >4x headroom, so unflagged decisions provably match fp64.
#define SCORE_MARGIN 1e-3f
#define ERR_MARGIN   1e-3f

static __device__ __forceinline__ unsigned short bf16_rne(float v) {
    __hip_bfloat16 h = __float2bfloat16(v);
    union { __hip_bfloat16 h; unsigned short u; } cv; cv.h = h; return cv.u;
}

// ---------------------------------------------------------------------------
// Fused single kernel. Per wave: 8 input rows x 2 branches = 16 A-rows.
// Scores via mfma_f32_16x16x32_bf16: A k0-7 = bf16_hi(ya), k8-15 = bf16_lo
// residual, k16 = 1.0, rest 0; B (LDS tiles) k0-7 = g, k8-15 = g, k16 = -n/2,
// rest 0  =>  D = hi.g + lo.g - n/2  (score' = dot - n/2, exact to ~2e-4).
// Per-lane tracking of (best, sec, q) on 4 C-regs, 4-level butterfly reduce
// over the 16 cols, fp32 epilogue (R6-verified), inline wave-cooperative fp64
// fixup (R2-verified arithmetic) for margin-flagged rows. One dispatch.
// Output d_out (float32): [final_vals (N*8) | final_idxs (N)].
// ---------------------------------------------------------------------------
__global__ __launch_bounds__(TPB) void e8p_fused(
    const float* __restrict__ X,
    const float* __restrict__ grid_part,
    const float* __restrict__ grid_part_norm,
    const int*   __restrict__ allcombo_idx,
    const int*   __restrict__ idx_map,
    float* __restrict__ out,
    int N, int G, int T)
{
    extern __shared__ __align__(16) unsigned char smem[];
    // tile t: [g-chunk: 16 cw x 8 bf16 = 256B][norm-chunk: 16 x [-n/2,0x7] = 256B]
    // zero block (16B) at T*512 for quad-3 B reads.

    const int tid = threadIdx.x;

    // ---------------- stage codebook ----------------
    for (int c = tid; c < T * 16; c += TPB) {
        const int t = c >> 4, n = c & 15;
        uint4 gv, nv;
        if (c < G) {
            const float4 g0 = *(const float4*)(grid_part + (size_t)c * 8);
            const float4 g1 = *(const float4*)(grid_part + (size_t)c * 8 + 4);
            gv.x = (unsigned)bf16_rne(g0.x) | ((unsigned)bf16_rne(g0.y) << 16);
            gv.y = (unsigned)bf16_rne(g0.z) | ((unsigned)bf16_rne(g0.w) << 16);
            gv.z = (unsigned)bf16_rne(g1.x) | ((unsigned)bf16_rne(g1.y) << 16);
            gv.w = (unsigned)bf16_rne(g1.z) | ((unsigned)bf16_rne(g1.w) << 16);
            nv.x = (unsigned)bf16_rne(-0.5f * grid_part_norm[c]);   // bf16-exact
        } else {
            gv.x = gv.y = gv.z = gv.w = 0u;         // pad codeword: score -30000
            nv.x = (unsigned)bf16_rne(-30000.0f);
        }
        nv.y = nv.z = nv.w = 0u;
        *(uint4*)(smem + (size_t)t * 512 +       n * 16) = gv;
        *(uint4*)(smem + (size_t)t * 512 + 256 + n * 16) = nv;
    }
    if (tid == 0) {
        uint4 z; z.x = z.y = z.z = z.w = 0u;
        *(uint4*)(smem + (size_t)T * 512) = z;
    }
    __syncthreads();

    const int lane = tid & 63;
    const int quad = lane >> 4;
    const int col  = lane & 15;
    const int wave = blockIdx.x * (TPB / 64) + (tid >> 6);

    const int m      = col;          // this lane's A-row (0..15)
    const int li     = m >> 1;       // local input row 0..7
    const int branch = m & 1;        // 0: +0.25, 1: -0.25
    const int irow   = wave * 8 + li;
    const int iload  = (irow < N) ? irow : 0;

    float x[8];
    {
        const float4 a = *(const float4*)(X + (size_t)iload * 8);
        const float4 b = *(const float4*)(X + (size_t)iload * 8 + 4);
        x[0]=a.x; x[1]=a.y; x[2]=a.z; x[3]=a.w;
        x[4]=b.x; x[5]=b.y; x[6]=b.z; x[7]=b.w;
    }

    // Branch prep (fp32 signs == fp64 signs: correctly-rounded add can't cross 0)
    float ya[8]; int neg = 0;
    const float sh = branch ? -0.25f : 0.25f;
#pragma unroll
    for (int j = 0; j < 8; ++j) {
        const float yj = x[j] + sh;
        if (yj < 0.0f) neg |= (1 << (7 - j));
        ya[j] = fabsf(yj);
    }
    int mint = neg;
    if (__popc(neg) & 1) { ya[0] = -ya[0]; mint ^= 128; }

    // A fragment by quad: q0 = hi(ya), q1 = lo(ya), q2 = [1,0..], q3 = 0
    bf16x8 afrag;
#pragma unroll
    for (int j = 0; j < 8; ++j) {
        const unsigned short hi = bf16_rne(ya[j]);
        const unsigned short lo = bf16_rne(ya[j] - __uint_as_float(((unsigned)hi) << 16));
        unsigned short v;
        if (quad == 0)      v = hi;
        else if (quad == 1) v = lo;
        else if (quad == 2) v = (j == 0) ? (unsigned short)0x3F80 : (unsigned short)0;
        else                v = 0;
        afrag[j] = (short)v;
    }

    // B address: quads 0,1 -> g-chunk; quad 2 -> norm-chunk; quad 3 -> zeros
    const int zeroOff = T * 512;
    const int offA = ((quad == 2) ? 256 : 0) + col * 16;
    const bool q3 = (quad == 3);

    float best[4] = {-1e30f,-1e30f,-1e30f,-1e30f};
    float sec[4]  = {-1e30f,-1e30f,-1e30f,-1e30f};
    int   q[4]    = {0,0,0,0};
    int   jcur    = col;

    const f32x4 czero = {0.0f, 0.0f, 0.0f, 0.0f};
    for (int t = 0; t < T; ++t) {
        const int addr = q3 ? zeroOff : (t * 512 + offA);
        const bf16x8 bfrag = *(const bf16x8*)(smem + addr);
        const f32x4 d = __builtin_amdgcn_mfma_f32_16x16x32_bf16(afrag, bfrag, czero, 0, 0, 0);
#pragma unroll
        for (int r = 0; r < 4; ++r) {
            const float s = d[r];
            const bool gt = s > best[r];                       // first-max-wins
            sec[r]  = __builtin_amdgcn_fmed3f(s, best[r], sec[r]);
            best[r] = fmaxf(best[r], s);
            q[r]    = gt ? jcur : q[r];
        }
        jcur += 16;
    }

    // Butterfly over the 16 cols (rows live in fixed reg r of this quad-group).
    // Lexicographic (max score, min index) == np.argmax; sec_union =
    // max(sec_a, sec_b, min(best_a, best_b)).
#pragma unroll
    for (int r = 0; r < 4; ++r) {
#pragma unroll
        for (int off = 1; off <= 8; off <<= 1) {
            const float ob = __shfl_xor(best[r], off, 64);
            const float os = __shfl_xor(sec[r],  off, 64);
            const int   oq = __shfl_xor(q[r],    off, 64);
            const float bmin = fminf(best[r], ob);
            sec[r] = fmaxf(fmaxf(sec[r], os), bmin);
            const bool take = (ob > best[r]) || ((ob == best[r]) && (oq < q[r]));
            best[r] = fmaxf(best[r], ob);
            q[r] = take ? oq : q[r];
        }
    }

    // ---- epilogue: lanes (quad, col<2) own input row liE = quad*2 + col ----
    const int liE  = quad * 2 + (col & 1);
    const int iE   = wave * 8 + liE;
    const int srcP = liE * 2;            // owner lane: x + mint of branch +
    const int srcM = liE * 2 + 1;

    float xe[8];
#pragma unroll
    for (int j = 0; j < 8; ++j) xe[j] = __shfl(x[j], srcP, 64);
    const int mintp = __shfl(mint, srcP, 64);
    const int mintm = __shfl(mint, srcM, 64);

    const bool hi2 = (col & 1);
    const float bBp = hi2 ? best[2] : best[0];
    const float sBp = hi2 ? sec[2]  : sec[0];
    const int   qP  = hi2 ? q[2]    : q[0];
    const float bBm = hi2 ? best[3] : best[1];
    const float sBm = hi2 ? sec[3]  : sec[1];
    const int   qM  = hi2 ? q[3]    : q[1];

    const bool doEpi = (col < 2) && (iE < N);
    bool close = false;
    if (doEpi) {
        const float* gp_ = grid_part + (size_t)qP * 8;
        const float* gm_ = grid_part + (size_t)qM * 8;
        float vp[8], vm[8];
        float ep2 = 0.0f, em2 = 0.0f;
        bool coin = true;
#pragma unroll
        for (int j = 0; j < 8; ++j) {
            const float maskp = ((mintp >> (7 - j)) & 1) ? -1.0f : 1.0f;
            const float maskm = ((mintm >> (7 - j)) & 1) ? -1.0f : 1.0f;
            vp[j] = gp_[j] * maskp;
            vm[j] = gm_[j] * maskm;
            coin = coin && ((vp[j] - 0.25f) == (vm[j] + 0.25f));  // exact fp32
            const float dpj = (xe[j] + 0.25f) - vp[j];
            const float dmj = (xe[j] - 0.25f) - vm[j];
            ep2 = fmaf(dpj, dpj, ep2);
            em2 = fmaf(dmj, dmj, em2);
        }
        close = ((bBp - sBp) < SCORE_MARGIN) | ((bBm - sBm) < SCORE_MARGIN) |
                (!coin && (fabsf(ep2 - em2) < ERR_MARGIN));
        if (!close) {
            // Coincident -> fp64 ref has pe==me bit-exactly -> which=false.
            const bool which = coin ? false : (ep2 < em2);
            const int rowp = idx_map[mintp];
            const int rowm = idx_map[mintm];
            const int pi = allcombo_idx[(size_t)rowp * G + qP];
            const int mi = allcombo_idx[(size_t)rowm * G + qM];
            const float idxval = which ? (float)pi : (float)(mi - 32768);
            float* vout = out + (size_t)iE * 8;
#pragma unroll
            for (int j = 0; j < 8; ++j)
                vout[j] = which ? (vp[j] - 0.25f) : (vm[j] + 0.25f);
            out[(size_t)N * 8 + iE] = idxval;
        }
    }

    // ---- inline fp64 fixup for flagged rows (R2-verified arithmetic) ----
    unsigned long long mb = __ballot(doEpi && close);
    while (mb) {
        const int b = (int)__ffsll(mb) - 1;
        mb &= (mb - 1);
        const int liF = (((b >> 4) & 3) << 1) | (b & 1);
        const int iF  = wave * 8 + liF;
        float xf[8];
#pragma unroll
        for (int j = 0; j < 8; ++j) xf[j] = __shfl(x[j], liF * 2, 64);

        double yapF[8], yamF[8];
        int negp = 0, negm = 0;
#pragma unroll
        for (int j = 0; j < 8; ++j) {
            const double xd = (double)xf[j];
            const double ypd = xd + 0.25;
            const double ymd = xd - 0.25;
            if (ypd < 0.0) negp |= (1 << (7 - j));
            if (ymd < 0.0) negm |= (1 << (7 - j));
            yapF[j] = fabs(ypd);
            yamF[j] = fabs(ymd);
        }
        int mintpF = negp, mintmF = negm;
        if (__popc(negp) & 1) { yapF[0] = -yapF[0]; mintpF ^= 128; }
        if (__popc(negm) & 1) { yamF[0] = -yamF[0]; mintmF ^= 128; }

        double bestpF = -1e300, bestmF = -1e300;
        int qpF = 0x7fffffff, qmF = 0x7fffffff;
        for (int j = lane; j < G; j += 64) {
            const float4 g0 = *(const float4*)(grid_part + (size_t)j * 8);
            const float4 g1 = *(const float4*)(grid_part + (size_t)j * 8 + 4);
            const double n = (double)grid_part_norm[j];
            const double t0 = (double)g0.x, t1 = (double)g0.y,
                         t2 = (double)g0.z, t3 = (double)g0.w,
                         t4 = (double)g1.x, t5 = (double)g1.y,
                         t6 = (double)g1.z, t7 = (double)g1.w;
            double dp, dm;
            dp = yapF[0] * t0;           dm = yamF[0] * t0;
            dp = fma(yapF[1], t1, dp);   dm = fma(yamF[1], t1, dm);
            dp = fma(yapF[2], t2, dp);   dm = fma(yamF[2], t2, dm);
            dp = fma(yapF[3], t3, dp);   dm = fma(yamF[3], t3, dm);
            dp = fma(yapF[4], t4, dp);   dm = fma(yamF[4], t4, dm);
            dp = fma(yapF[5], t5, dp);   dm = fma(yamF[5], t5, dm);
            dp = fma(yapF[6], t6, dp);   dm = fma(yamF[6], t6, dm);
            dp = fma(yapF[7], t7, dp);   dm = fma(yamF[7], t7, dm);
            const double sp = 2.0 * dp - n;
            const double sm = 2.0 * dm - n;
            if (sp > bestpF) { bestpF = sp; qpF = j; }
            if (sm > bestmF) { bestmF = sm; qmF = j; }
        }
#pragma unroll
        for (int off = 32; off > 0; off >>= 1) {
            double ob = __shfl_xor(bestpF, off, 64);
            int    oq = __shfl_xor(qpF, off, 64);
            if (ob > bestpF || (ob == bestpF && oq < qpF)) { bestpF = ob; qpF = oq; }
            ob = __shfl_xor(bestmF, off, 64);
            oq = __shfl_xor(qmF, off, 64);
            if (ob > bestmF || (ob == bestmF && oq < qmF)) { bestmF = ob; qmF = oq; }
        }
        if (lane == 0) {
            const float* gp_ = grid_part + (size_t)qpF * 8;
            const float* gm_ = grid_part + (size_t)qmF * 8;
            double vp[8], vm[8];
            double ep2 = 0.0, em2 = 0.0;
#pragma unroll
            for (int j = 0; j < 8; ++j) {
                const double maskp = ((mintpF >> (7 - j)) & 1) ? -1.0 : 1.0;
                const double maskm = ((mintmF >> (7 - j)) & 1) ? -1.0 : 1.0;
                vp[j] = (double)gp_[j] * maskp;
                vm[j] = (double)gm_[j] * maskm;
                const double xd = (double)xf[j];
                const double dpj = (xd + 0.25) - vp[j];
                const double dmj = (xd - 0.25) - vm[j];
                ep2 += dpj * dpj;
                em2 += dmj * dmj;
            }
            const double ep = sqrt(ep2), em = sqrt(em2);
            const bool which = ep < em;
            const int rowp = idx_map[mintpF];
            const int rowm = idx_map[mintmF];
            const int pi = allcombo_idx[(size_t)rowp * G + qpF];
            const int mi = allcombo_idx[(size_t)rowm * G + qmF];
            const float idxval = which ? (float)pi : (float)(mi - 32768);
            float* vout = out + (size_t)iF * 8;
#pragma unroll
            for (int j = 0; j < 8; ++j) {
                const double v = which ? (vp[j] - 0.25) : (vm[j] + 0.25);
                vout[j] = (float)v;
            }
            out[(size_t)N * 8 + iF] = idxval;
        }
    }
}

extern "C" void kernel_launch(void* const* d_in, const int* in_sizes, int n_in,
                              void* d_out, int out_size, void* d_ws, size_t ws_size,
                              hipStream_t stream) {
    const float* X    = (const float*)d_in[0];
    const float* gp   = (const float*)d_in[1];
    const float* gn   = (const float*)d_in[2];
    const int*   aci  = (const int*)d_in[3];
    const int*   imap = (const int*)d_in[4];
    // d_in[5] (int_map) and d_in[6] (grid_idx_map) are folded analytically.

    const int N = in_sizes[0] / 8;
    const int G = in_sizes[1] / 8;
    const int T = (G + 15) / 16;                    // B-tiles of 16 codewords
    const int blocks = (N + 31) / 32;               // 4 waves x 8 rows per block
    const size_t shmem = (size_t)T * 512 + 16;      // tiles + zero block (~44KB)

    hipLaunchKernelGGL(e8p_fused, dim3(blocks), dim3(TPB), shmem, stream,
                       X, gp, gn, aci, imap, (float*)d_out, N, G, T);
}

// Round 8
// 169.441 us; speedup vs baseline: 2.2439x; 1.1682x over previous
//
#include <hip/hip_runtime.h>
#include <hip/hip_bf16.h>

typedef __attribute__((ext_vector_type(8)))  short bf16x8;
typedef __attribute__((ext_vector_type(16))) float f32x16;

#define TPB 256
// MFMA score error bound ~1e-4 (bf16 hi/lo split of ya, fp32 accumulate, C-add);
// 1e-3 margin gives ~10x headroom -> unflagged decisions provably match fp64.
#define SCORE_MARGIN 1e-3f
#define ERR_MARGIN   1e-3f

static __device__ __forceinline__ unsigned short bf16_rne(float v) {
    union { __hip_bfloat16 h; unsigned short u; } cv;
    cv.h = __float2bfloat16(v);
    return cv.u;
}

// ---------------------------------------------------------------------------
// Single fused kernel, mfma_f32_32x32x16_bf16, orientation: A = codewords
// (M=32 cw/tile, K=16 = 8 dims x {hi,lo}; A row = [g|g], so both k-halves read
// the SAME 16B -> 1 broadcast ds_read_b128 per tile), B = ya (N=32 = 16 input
// rows x 2 branches, loop-invariant: k0-7 = bf16_hi(ya), k8-15 = bf16_lo
// residual), C = -norm/2 preloaded from LDS in the exact C/D register order
// (row=(reg&3)+8*(reg>>2)+4*(lane>>5), verified layout) -> D = hi.g + lo.g
// - n/2 = score' with zero per-tile VALU for the norm.
// Tracking: 16 slots/lane (4 inst/score), 15 in-lane merges + 1 butterfly
// level (offset 32) + pair swap (offset 1). fp32 epilogue + margin flags +
// inline wave-cooperative fp64 fixup (R2-verified arithmetic, absmax 0 since
// R3). Output d_out (float32): [final_vals (N*8) | final_idxs (N)].
// ---------------------------------------------------------------------------
__global__ __launch_bounds__(TPB) void e8p_fused(
    const float* __restrict__ X,
    const float* __restrict__ grid_part,
    const float* __restrict__ grid_part_norm,
    const int*   __restrict__ allcombo_idx,
    const int*   __restrict__ idx_map,
    float* __restrict__ out,
    int N, int G, int T)
{
    extern __shared__ __align__(16) unsigned char smem[];
    const int T32 = T * 32;
    unsigned char* ldsG = smem;                          // T32 cw x 16B bf16x8
    float* ldsN = (float*)(smem + (size_t)T32 * 16);     // T32 floats, permuted

    const int tid = threadIdx.x;

    // ---- stage codebook: g as bf16x8 (exact), norms permuted to C-reg order
    for (int c = tid; c < T32; c += TPB) {
        uint4 gv; float nv;
        if (c < G) {
            const float4 g0 = *(const float4*)(grid_part + (size_t)c * 8);
            const float4 g1 = *(const float4*)(grid_part + (size_t)c * 8 + 4);
            gv.x = (unsigned)bf16_rne(g0.x) | ((unsigned)bf16_rne(g0.y) << 16);
            gv.y = (unsigned)bf16_rne(g0.z) | ((unsigned)bf16_rne(g0.w) << 16);
            gv.z = (unsigned)bf16_rne(g1.x) | ((unsigned)bf16_rne(g1.y) << 16);
            gv.w = (unsigned)bf16_rne(g1.z) | ((unsigned)bf16_rne(g1.w) << 16);
            nv = -0.5f * grid_part_norm[c];
        } else {
            gv.x = gv.y = gv.z = gv.w = 0u;  // pad cw: dot 0, norm-slot -30000
            nv = -30000.0f;
        }
        *(uint4*)(ldsG + (size_t)c * 16) = gv;
        // cw row w = 8g + 4h + j  ->  store at t*32 + h*16 + g*4 + j
        const int t = c >> 5, w = c & 31;
        ldsN[t * 32 + ((w >> 2) & 1) * 16 + (w >> 3) * 4 + (w & 3)] = nv;
    }
    __syncthreads();

    const int lane = tid & 63;
    const int h    = lane >> 5;        // k-half / C-row offset 4h
    const int col  = lane & 31;        // B col = (input row, branch)
    const int wave = blockIdx.x * (TPB / 64) + (tid >> 6);

    const int li     = col >> 1;
    const int branch = col & 1;        // 0: +0.25, 1: -0.25
    const int irow   = wave * 16 + li;
    const int iload  = (irow < N) ? irow : 0;

    float x[8];
    {
        const float4 a = *(const float4*)(X + (size_t)iload * 8);
        const float4 b = *(const float4*)(X + (size_t)iload * 8 + 4);
        x[0]=a.x; x[1]=a.y; x[2]=a.z; x[3]=a.w;
        x[4]=b.x; x[5]=b.y; x[6]=b.z; x[7]=b.w;
    }

    // Branch prep (fp32 signs == fp64 signs: correctly-rounded add can't cross 0)
    float ya[8]; int neg = 0;
    const float sh = branch ? -0.25f : 0.25f;
#pragma unroll
    for (int j = 0; j < 8; ++j) {
        const float yj = x[j] + sh;
        if (yj < 0.0f) neg |= (1 << (7 - j));
        ya[j] = fabsf(yj);
    }
    int mint = neg;
    if (__popc(neg) & 1) { ya[0] = -ya[0]; mint ^= 128; }

    // B fragment (loop-invariant): h=0 -> bf16_hi(ya), h=1 -> bf16_lo residual
    bf16x8 bfrag;
#pragma unroll
    for (int j = 0; j < 8; ++j) {
        const unsigned short hi = bf16_rne(ya[j]);
        const unsigned short lo = bf16_rne(ya[j] - __uint_as_float(((unsigned)hi) << 16));
        bfrag[j] = (short)(h ? lo : hi);
    }

    float best[16], sec[16]; int q[16];
#pragma unroll
    for (int r = 0; r < 16; ++r) { best[r] = -1e30f; sec[r] = -1e30f; q[r] = 0; }

    const unsigned aoff = (unsigned)col * 16u;
    for (int t = 0; t < T; ++t) {
        const bf16x8 afrag = *(const bf16x8*)(ldsG + (size_t)t * 512 + aoff);
        const float* nb = ldsN + t * 32 + h * 16;
        const float4 c0 = *(const float4*)(nb);
        const float4 c1 = *(const float4*)(nb + 4);
        const float4 c2 = *(const float4*)(nb + 8);
        const float4 c3 = *(const float4*)(nb + 12);
        f32x16 cf;
        cf[0]=c0.x; cf[1]=c0.y; cf[2]=c0.z; cf[3]=c0.w;
        cf[4]=c1.x; cf[5]=c1.y; cf[6]=c1.z; cf[7]=c1.w;
        cf[8]=c2.x; cf[9]=c2.y; cf[10]=c2.z; cf[11]=c2.w;
        cf[12]=c3.x; cf[13]=c3.y; cf[14]=c3.z; cf[15]=c3.w;
        const f32x16 d = __builtin_amdgcn_mfma_f32_32x32x16_bf16(afrag, bfrag, cf, 0, 0, 0);
#pragma unroll
        for (int r = 0; r < 16; ++r) {
            const float s = d[r];
            const bool gt = s > best[r];              // first-max-wins per slot
            sec[r]  = __builtin_amdgcn_fmed3f(s, best[r], sec[r]);
            best[r] = fmaxf(best[r], s);
            q[r]    = gt ? t : q[r];
        }
    }

    // ---- reduce 16 slots -> 1 (lexicographic max-score, min-index; second =
    // max(secs, min(bests)) so equal-best distinct codewords flag the margin)
    float bb = best[0], ss = sec[0];
    int   ii = 32 * q[0] + 4 * h;                     // r=0 rowoff = 4h
#pragma unroll
    for (int r = 1; r < 16; ++r) {
        const int rowoff = (r & 3) + 8 * (r >> 2) + 4 * h;
        const int idx = 32 * q[r] + rowoff;
        const float br = best[r];
        ss = fmaxf(fmaxf(ss, sec[r]), fminf(bb, br));
        const bool take = (br > bb) || ((br == bb) && (idx < ii));
        bb = fmaxf(bb, br);
        ii = take ? idx : ii;
    }
    {   // butterfly across the two k-half lane groups (offset 32)
        const float ob = __shfl_xor(bb, 32, 64);
        const float os = __shfl_xor(ss, 32, 64);
        const int   oi = __shfl_xor(ii, 32, 64);
        ss = fmaxf(fmaxf(ss, os), fminf(bb, ob));
        const bool take = (ob > bb) || ((ob == bb) && (oi < ii));
        bb = fmaxf(bb, ob);
        ii = take ? oi : ii;
    }
    // pair swap: even col (plus branch) receives odd col (minus branch)
    const float bbO   = __shfl_xor(bb, 1, 64);
    const float ssO   = __shfl_xor(ss, 1, 64);
    const int   iiO   = __shfl_xor(ii, 1, 64);
    const int   mintO = __shfl_xor(mint, 1, 64);

    const bool doEpi = (h == 0) && (branch == 0) && (irow < N);
    bool close = false;
    if (doEpi) {
        const int qP = ii, qM = iiO;
        const float* gp_ = grid_part + (size_t)qP * 8;
        const float* gm_ = grid_part + (size_t)qM * 8;
        float vp[8], vm[8];
        float ep2 = 0.0f, em2 = 0.0f;
        bool coin = true;
#pragma unroll
        for (int j = 0; j < 8; ++j) {
            const float maskp = ((mint  >> (7 - j)) & 1) ? -1.0f : 1.0f;
            const float maskm = ((mintO >> (7 - j)) & 1) ? -1.0f : 1.0f;
            vp[j] = gp_[j] * maskp;
            vm[j] = gm_[j] * maskm;
            coin = coin && ((vp[j] - 0.25f) == (vm[j] + 0.25f));  // exact fp32
            const float dpj = (x[j] + 0.25f) - vp[j];
            const float dmj = (x[j] - 0.25f) - vm[j];
            ep2 = fmaf(dpj, dpj, ep2);
            em2 = fmaf(dmj, dmj, em2);
        }
        close = ((bb - ss) < SCORE_MARGIN) | ((bbO - ssO) < SCORE_MARGIN) |
                (!coin && (fabsf(ep2 - em2) < ERR_MARGIN));
        if (!close) {
            // Coincident -> fp64 ref has pe==me bit-exactly -> which=false.
            const bool which = coin ? false : (ep2 < em2);
            const int rowp = idx_map[mint];
            const int rowm = idx_map[mintO];
            const int pi = allcombo_idx[(size_t)rowp * G + qP];
            const int mi = allcombo_idx[(size_t)rowm * G + qM];
            const float idxval = which ? (float)pi : (float)(mi - 32768);
            float* vout = out + (size_t)irow * 8;
#pragma unroll
            for (int j = 0; j < 8; ++j)
                vout[j] = which ? (vp[j] - 0.25f) : (vm[j] + 0.25f);
            out[(size_t)N * 8 + irow] = idxval;
        }
    }

    // ---- inline fp64 fixup for flagged rows (R2-verified arithmetic) ----
    unsigned long long mb = __ballot(doEpi && close);
    while (mb) {
        const int b = (int)__ffsll(mb) - 1;   // flagged lane: h=0, even col
        mb &= (mb - 1);
        const int liF = b >> 1;
        const int iF  = wave * 16 + liF;
        float xf[8];
#pragma unroll
        for (int j = 0; j < 8; ++j) xf[j] = __shfl(x[j], b, 64);

        double yapF[8], yamF[8];
        int negp = 0, negm = 0;
#pragma unroll
        for (int j = 0; j < 8; ++j) {
            const double xd = (double)xf[j];
            const double ypd = xd + 0.25;
            const double ymd = xd - 0.25;
            if (ypd < 0.0) negp |= (1 << (7 - j));
            if (ymd < 0.0) negm |= (1 << (7 - j));
            yapF[j] = fabs(ypd);
            yamF[j] = fabs(ymd);
        }
        int mintpF = negp, mintmF = negm;
        if (__popc(negp) & 1) { yapF[0] = -yapF[0]; mintpF ^= 128; }
        if (__popc(negm) & 1) { yamF[0] = -yamF[0]; mintmF ^= 128; }

        double bestpF = -1e300, bestmF = -1e300;
        int qpF = 0x7fffffff, qmF = 0x7fffffff;
        for (int j = lane; j < G; j += 64) {
            const float4 g0 = *(const float4*)(grid_part + (size_t)j * 8);
            const float4 g1 = *(const float4*)(grid_part + (size_t)j * 8 + 4);
            const double n = (double)grid_part_norm[j];
            const double t0 = (double)g0.x, t1 = (double)g0.y,
                         t2 = (double)g0.z, t3 = (double)g0.w,
                         t4 = (double)g1.x, t5 = (double)g1.y,
                         t6 = (double)g1.z, t7 = (double)g1.w;
            double dp, dm;
            dp = yapF[0] * t0;           dm = yamF[0] * t0;
            dp = fma(yapF[1], t1, dp);   dm = fma(yamF[1], t1, dm);
            dp = fma(yapF[2], t2, dp);   dm = fma(yamF[2], t2, dm);
            dp = fma(yapF[3], t3, dp);   dm = fma(yamF[3], t3, dm);
            dp = fma(yapF[4], t4, dp);   dm = fma(yamF[4], t4, dm);
            dp = fma(yapF[5], t5, dp);   dm = fma(yamF[5], t5, dm);
            dp = fma(yapF[6], t6, dp);   dm = fma(yamF[6], t6, dm);
            dp = fma(yapF[7], t7, dp);   dm = fma(yamF[7], t7, dm);
            const double sp = 2.0 * dp - n;
            const double sm = 2.0 * dm - n;
            if (sp > bestpF) { bestpF = sp; qpF = j; }
            if (sm > bestmF) { bestmF = sm; qmF = j; }
        }
#pragma unroll
        for (int off = 32; off > 0; off >>= 1) {
            double ob = __shfl_xor(bestpF, off, 64);
            int    oq = __shfl_xor(qpF, off, 64);
            if (ob > bestpF || (ob == bestpF && oq < qpF)) { bestpF = ob; qpF = oq; }
            ob = __shfl_xor(bestmF, off, 64);
            oq = __shfl_xor(qmF, off, 64);
            if (ob > bestmF || (ob == bestmF && oq < qmF)) { bestmF = ob; qmF = oq; }
        }
        if (lane == 0) {
            const float* gp_ = grid_part + (size_t)qpF * 8;
            const float* gm_ = grid_part + (size_t)qmF * 8;
            double vp[8], vm[8];
            double ep2 = 0.0, em2 = 0.0;
#pragma unroll
            for (int j = 0; j < 8; ++j) {
                const double maskp = ((mintpF >> (7 - j)) & 1) ? -1.0 : 1.0;
                const double maskm = ((mintmF >> (7 - j)) & 1) ? -1.0 : 1.0;
                vp[j] = (double)gp_[j] * maskp;
                vm[j] = (double)gm_[j] * maskm;
                const double xd = (double)xf[j];
                const double dpj = (xd + 0.25) - vp[j];
                const double dmj = (xd - 0.25) - vm[j];
                ep2 += dpj * dpj;
                em2 += dmj * dmj;
            }
            const double ep = sqrt(ep2), em = sqrt(em2);
            const bool which = ep < em;
            const int rowp = idx_map[mintpF];
            const int rowm = idx_map[mintmF];
            const int pi = allcombo_idx[(size_t)rowp * G + qpF];
            const int mi = allcombo_idx[(size_t)rowm * G + qmF];
            const float idxval = which ? (float)pi : (float)(mi - 32768);
            float* vout = out + (size_t)iF * 8;
#pragma unroll
            for (int j = 0; j < 8; ++j) {
                const double v = which ? (vp[j] - 0.25) : (vm[j] + 0.25);
                vout[j] = (float)v;
            }
            out[(size_t)N * 8 + iF] = idxval;
        }
    }
}

extern "C" void kernel_launch(void* const* d_in, const int* in_sizes, int n_in,
                              void* d_out, int out_size, void* d_ws, size_t ws_size,
                              hipStream_t stream) {
    const float* X    = (const float*)d_in[0];
    const float* gp   = (const float*)d_in[1];
    const float* gn   = (const float*)d_in[2];
    const int*   aci  = (const int*)d_in[3];
    const int*   imap = (const int*)d_in[4];
    // d_in[5] (int_map) and d_in[6] (grid_idx_map) are folded analytically.

    const int N = in_sizes[0] / 8;
    const int G = in_sizes[1] / 8;
    const int T = (G + 31) / 32;                 // tiles of 32 codewords
    const int blocks = (N + 63) / 64;            // 4 waves x 16 rows per block
    const size_t shmem = (size_t)T * 32 * 16 + (size_t)T * 32 * 4;  // ~27.5KB

    hipLaunchKernelGGL(e8p_fused, dim3(blocks), dim3(TPB), shmem, stream,
                       X, gp, gn, aci, imap, (float*)d_out, N, G, T);
}